// Round 11
// baseline (105.911 us; speedup 1.0000x reference)
//
#include <hip/hip_runtime.h>
#include <hip/hip_bf16.h>
#include <math.h>

// Problem constants (fixed shape)
#define T_ 1024
#define H_ 1024
#define I_ 2048
#define E_ 8
#define NSLOT 2048

// GEMM tiling
#define BM 128
#define BK 32
#define BN1 64
#define BN2 64
#define NCHUNK_CAP 24
#define SPLITK2 2

typedef __attribute__((ext_vector_type(8))) short bf16x8;
typedef __attribute__((ext_vector_type(4))) float f32x4;
typedef __attribute__((ext_vector_type(4))) unsigned uint4v;
typedef __attribute__((ext_vector_type(2))) unsigned uint2v;

#define MFMA_BF16 __builtin_amdgcn_mfma_f32_16x16x32_bf16

__device__ __forceinline__ short f2bf(float f) {
  union { float f; unsigned u; } v; v.f = f;
  unsigned r = v.u + 0x7FFFu + ((v.u >> 16) & 1u);
  return (short)(r >> 16);
}
__device__ __forceinline__ unsigned cvtpk(float lo, float hi) {
  unsigned r;
  asm("v_cvt_pk_bf16_f32 %0, %1, %2" : "=v"(r) : "v"(lo), "v"(hi));
  return r;
}
__device__ __forceinline__ void gll16(const void* g, void* l) {
  __builtin_amdgcn_global_load_lds(
      (const __attribute__((address_space(1))) void*)g,
      (__attribute__((address_space(3))) void*)l, 16, 0, 0);
}

// Phase barriers. Issue order inside a phase is pinned: glls FIRST, then
// B-register loads (sched_barrier between). vmcnt(N) = number of B-loads
// allowed to remain in flight; it forces the older glls (whose LDS data the
// NEXT phase's MFMA reads) to retire before the barrier.
__device__ __forceinline__ void pipe_barrier8() {   // gemm1: keep 8 B-loads
  __builtin_amdgcn_sched_barrier(0);
  asm volatile("s_waitcnt vmcnt(8) lgkmcnt(0)" ::: "memory");
  __builtin_amdgcn_s_barrier();
  __builtin_amdgcn_sched_barrier(0);
}
__device__ __forceinline__ void pipe_barrier4() {   // gemm2: keep 4 B-loads
  __builtin_amdgcn_sched_barrier(0);
  asm volatile("s_waitcnt vmcnt(4) lgkmcnt(0)" ::: "memory");
  __builtin_amdgcn_s_barrier();
  __builtin_amdgcn_sched_barrier(0);
}
__device__ __forceinline__ void drain_barrier() {
  __builtin_amdgcn_sched_barrier(0);
  asm volatile("s_waitcnt vmcnt(0) lgkmcnt(0)" ::: "memory");
  __builtin_amdgcn_s_barrier();
  __builtin_amdgcn_sched_barrier(0);
}
__device__ __forceinline__ void no_barrier() {}

// B-tile swizzle ([n][k] bf16, rows of 64B) — gemm2 layout.
__device__ __forceinline__ unsigned bswz(int n, int kbyte) {
  return (unsigned)(n * 64 + (kbyte ^ (((n >> 2) & 3) << 4)));
}
// Unified tile swizzle ([rows][32] bf16, four 16B granules) — gemm1 layout.
__device__ __forceinline__ int rswz(int row) { return (row >> 1) & 3; }
__device__ __forceinline__ unsigned tile_addr(int row, int g) {
  return (unsigned)(row * 64 + (((g ^ rswz(row)) & 3) << 4));
}

// ---------------------------------------------------------------------------
// Kernel 0: fused hs f32->bf16 convert (all blocks) + routing build (block 0)
// ---------------------------------------------------------------------------
__global__ __launch_bounds__(256) void k_prep_build(
    const float* __restrict__ hs, short* __restrict__ hs_bf,
    const float* __restrict__ aff, const int* __restrict__ eidx,
    int* __restrict__ meta, int* __restrict__ slot_tok, float* __restrict__ slot_w) {
  int i = (blockIdx.x * 256 + threadIdx.x) * 8;
  float4 v0 = *(const float4*)&hs[i];
  float4 v1 = *(const float4*)&hs[i + 4];
  uint4v p;
  p.x = cvtpk(v0.x, v0.y); p.y = cvtpk(v0.z, v0.w);
  p.z = cvtpk(v1.x, v1.y); p.w = cvtpk(v1.z, v1.w);
  *(uint4v*)&hs_bf[i] = p;

  if (blockIdx.x != 0) return;
  __shared__ int cnt[E_];
  __shared__ int soff[E_ + 1];
  int t = threadIdx.x;
  if (t < E_) cnt[t] = 0;
  __syncthreads();
  int e0a[4], e1a[4], r0a[4], r1a[4];
  float w0a[4], w1a[4];
#pragma unroll
  for (int j = 0; j < 4; ++j) {
    int tok = t + 256 * j;
    int e0 = eidx[tok * 2 + 0];
    int e1 = eidx[tok * 2 + 1];
    float a0 = aff[tok * E_ + e0];
    float a1 = aff[tok * E_ + e1];
    float inv = 1.0f / (a0 + a1);
    r0a[j] = atomicAdd(&cnt[e0], 1);
    r1a[j] = atomicAdd(&cnt[e1], 1);
    e0a[j] = e0; e1a[j] = e1;
    w0a[j] = a0 * inv; w1a[j] = a1 * inv;
  }
  __syncthreads();
  if (t == 0) {
    int s = 0;
    for (int e = 0; e < E_; ++e) { soff[e] = s; s += cnt[e]; }
    soff[E_] = s;
    int nc = 0;
    for (int e = 0; e < E_; ++e)
      for (int c = soff[e]; c < soff[e] + cnt[e]; c += BM)
        meta[16 + nc++] = e | (c << 8);
    meta[9] = nc;
  }
  __syncthreads();
  if (t <= E_) meta[t] = soff[t];
#pragma unroll
  for (int j = 0; j < 4; ++j) {
    int tok = t + 256 * j;
    int s0 = soff[e0a[j]] + r0a[j];
    int s1 = soff[e1a[j]] + r1a[j];
    slot_tok[s0] = tok; slot_w[s0] = w0a[j];
    slot_tok[s1] = tok; slot_w[s1] = w1a[j];
  }
}

// ---------------------------------------------------------------------------
// Kernel 1: grouped GEMM  act = silu(X@Wg) * (X@Wu)
// 2 K-tiles per barrier phase (16 barriers). Per phase: gll tiles T0+2/3
// (FIRST, forced retired at the phase barrier), B-reg loads for T0+4/5
// (2-phase distance, stay in flight), compute T0/T0+1, convert T0+2/3.
// ---------------------------------------------------------------------------
__global__ __launch_bounds__(256, 2) void k_gemm1(
    const short* __restrict__ hs_bf, const float* __restrict__ wg,
    const float* __restrict__ wu, const int* __restrict__ meta,
    const int* __restrict__ slot_tok, short* __restrict__ act) {
  int nch = meta[9];
  if (blockIdx.y >= nch) return;
  int ck = meta[16 + blockIdx.y];
  int e = ck & 255;
  int row0 = ck >> 8;
  int rows = min(BM, meta[1 + e] - row0);
  int i0 = blockIdx.x * BN1;

  __shared__ short sA[4][BM * BK];       // 32KB ring-4
  __shared__ short sB[4][2][BN1 * BK];   // 32KB ring-4 x {gate,up}

  int tid = threadIdx.x;
  int lane = tid & 63;
  int w = tid >> 6;
  int wm = w >> 1, wn = w & 1;
  int lr = lane & 15;
  int g = lane >> 4;

  const float* wgE = wg + (size_t)e * H_ * I_;
  const float* wuE = wu + (size_t)e * H_ * I_;

  int r_a0 = 32 * w + (lane >> 2);
  int r_a1 = r_a0 + 16;
  int tok0 = slot_tok[row0 + min(r_a0, rows - 1)];
  int tok1 = slot_tok[row0 + min(r_a1, rows - 1)];
  const short* srcA0 = hs_bf + (size_t)tok0 * H_ + ((((lane & 3) ^ rswz(r_a0)) & 3) << 3);
  const short* srcA1 = hs_bf + (size_t)tok1 * H_ + ((((lane & 3) ^ rswz(r_a1)) & 3) << 3);

  int mat = tid >> 7;
  int kq = (tid >> 4) & 7;
  int nq = tid & 15;
  const float* srcB = (mat ? wuE : wgE) + (size_t)(4 * kq) * I_ + i0 + 4 * nq;

  f32x4 accg[4][2], accu[4][2];
#pragma unroll
  for (int mf = 0; mf < 4; ++mf)
#pragma unroll
    for (int nf = 0; nf < 2; ++nf) {
      accg[mf][nf] = (f32x4){0.f, 0.f, 0.f, 0.f};
      accu[mf][nf] = (f32x4){0.f, 0.f, 0.f, 0.f};
    }

  f32x4 xA0[4], xA1[4], xB0[4], xB1[4];   // B reg sets (2 tiles each)

  const int NT = H_ / BK;   // 32

#define G1_GLL(T) do {                                                         \
    gll16(srcA0 + (size_t)(T) * BK, &sA[(T) & 3][(32 * w) * 32]);              \
    gll16(srcA1 + (size_t)(T) * BK, &sA[(T) & 3][(32 * w + 16) * 32]);         \
  } while (0)
#define G1_LOADB(C, T) do {                                                    \
    const float* sb_ = srcB + (size_t)(T) * BK * I_;                           \
    C[0] = *(const f32x4*)(sb_);                                               \
    C[1] = *(const f32x4*)(sb_ + I_);                                          \
    C[2] = *(const f32x4*)(sb_ + 2 * I_);                                      \
    C[3] = *(const f32x4*)(sb_ + 3 * I_);                                      \
  } while (0)
#define G1_CONV(T, C) do {                                                     \
    char* dst_ = (char*)&sB[(T) & 3][mat][0];                                  \
    _Pragma("unroll")                                                          \
    for (int c_ = 0; c_ < 4; ++c_) {                                           \
      int n_ = 4 * nq + c_;                                                    \
      uint2v wv_;                                                              \
      wv_.x = cvtpk(C[0][c_], C[1][c_]);                                       \
      wv_.y = cvtpk(C[2][c_], C[3][c_]);                                       \
      *(uint2v*)(dst_ + tile_addr(n_, kq >> 1) + ((kq & 1) << 3)) = wv_;       \
    }                                                                          \
  } while (0)
#define G1_COMPUTE(T) do {                                                     \
    const char* curA = (const char*)&sA[(T) & 3][0];                           \
    const char* pg = (const char*)&sB[(T) & 3][0][0];                          \
    const char* pu = (const char*)&sB[(T) & 3][1][0];                          \
    bf16x8 a0 = *(const bf16x8*)(curA + tile_addr(wm * 64 + lr, g));           \
    bf16x8 a1 = *(const bf16x8*)(curA + tile_addr(wm * 64 + 16 + lr, g));      \
    bf16x8 a2 = *(const bf16x8*)(curA + tile_addr(wm * 64 + 32 + lr, g));      \
    bf16x8 a3 = *(const bf16x8*)(curA + tile_addr(wm * 64 + 48 + lr, g));      \
    unsigned ob0 = tile_addr(wn * 32 + lr, g);                                 \
    unsigned ob1 = tile_addr(wn * 32 + 16 + lr, g);                            \
    bf16x8 g0 = *(const bf16x8*)(pg + ob0);                                    \
    bf16x8 g1 = *(const bf16x8*)(pg + ob1);                                    \
    bf16x8 u0 = *(const bf16x8*)(pu + ob0);                                    \
    bf16x8 u1 = *(const bf16x8*)(pu + ob1);                                    \
    accg[0][0] = MFMA_BF16(a0, g0, accg[0][0], 0, 0, 0);                       \
    accg[0][1] = MFMA_BF16(a0, g1, accg[0][1], 0, 0, 0);                       \
    accg[1][0] = MFMA_BF16(a1, g0, accg[1][0], 0, 0, 0);                       \
    accg[1][1] = MFMA_BF16(a1, g1, accg[1][1], 0, 0, 0);                       \
    accg[2][0] = MFMA_BF16(a2, g0, accg[2][0], 0, 0, 0);                       \
    accg[2][1] = MFMA_BF16(a2, g1, accg[2][1], 0, 0, 0);                       \
    accg[3][0] = MFMA_BF16(a3, g0, accg[3][0], 0, 0, 0);                       \
    accg[3][1] = MFMA_BF16(a3, g1, accg[3][1], 0, 0, 0);                       \
    accu[0][0] = MFMA_BF16(a0, u0, accu[0][0], 0, 0, 0);                       \
    accu[0][1] = MFMA_BF16(a0, u1, accu[0][1], 0, 0, 0);                       \
    accu[1][0] = MFMA_BF16(a1, u0, accu[1][0], 0, 0, 0);                       \
    accu[1][1] = MFMA_BF16(a1, u1, accu[1][1], 0, 0, 0);                       \
    accu[2][0] = MFMA_BF16(a2, u0, accu[2][0], 0, 0, 0);                       \
    accu[2][1] = MFMA_BF16(a2, u1, accu[2][1], 0, 0, 0);                       \
    accu[3][0] = MFMA_BF16(a3, u0, accu[3][0], 0, 0, 0);                       \
    accu[3][1] = MFMA_BF16(a3, u1, accu[3][1], 0, 0, 0);                       \
  } while (0)
// Phase: glls FIRST (pinned), then B-reg loads, compute, convert, barrier.
#define G1_PHASE(T0, LA, LB, CA, CB, BAR) do {                                 \
    if ((T0) + 2 < NT) { G1_GLL((T0) + 2); G1_GLL((T0) + 3); }                 \
    __builtin_amdgcn_sched_barrier(0);                                         \
    if ((T0) + 4 < NT) { G1_LOADB(LA, (T0) + 4); G1_LOADB(LB, (T0) + 5); }     \
    G1_COMPUTE(T0);                                                            \
    G1_COMPUTE((T0) + 1);                                                      \
    if ((T0) + 2 < NT) { G1_CONV((T0) + 2, CA); G1_CONV((T0) + 3, CB); }       \
    BAR();                                                                     \
  } while (0)

  // prologue: gll tiles 0-3; B tiles 0,1 -> sB[0],sB[1]; load 2,3; drain
  G1_GLL(0); G1_GLL(1); G1_GLL(2); G1_GLL(3);
  G1_LOADB(xB0, 0); G1_LOADB(xB1, 1);
  G1_CONV(0, xB0); G1_CONV(1, xB1);
  G1_LOADB(xA0, 2); G1_LOADB(xA1, 3);
  drain_barrier();

  for (int T0 = 0; T0 < 28; T0 += 4) {
    G1_PHASE(T0,     xB0, xB1, xA0, xA1, pipe_barrier8);
    G1_PHASE(T0 + 2, xA0, xA1, xB0, xB1, pipe_barrier8);
  }
  G1_PHASE(28, xB0, xB1, xA0, xA1, drain_barrier);   // conv tiles 30,31
  G1_PHASE(30, xA0, xA1, xB0, xB1, no_barrier);      // compute only

#undef G1_PHASE
#undef G1_COMPUTE
#undef G1_CONV
#undef G1_LOADB
#undef G1_GLL

  // epilogue: silu(g)*u -> bf16 act
#pragma unroll
  for (int mf = 0; mf < 4; ++mf) {
#pragma unroll
    for (int r = 0; r < 4; ++r) {
      int m = wm * 64 + mf * 16 + g * 4 + r;
      if (m < rows) {
#pragma unroll
        for (int nf = 0; nf < 2; ++nf) {
          float gv = accg[mf][nf][r];
          float uv = accu[mf][nf][r];
          float sg = 1.0f / (1.0f + __expf(-gv));
          act[(size_t)(row0 + m) * I_ + i0 + wn * 32 + nf * 16 + lr] = f2bf(gv * sg * uv);
        }
      }
    }
  }
}

// ---------------------------------------------------------------------------
// Kernel 2: down-proj  out[tok,h] += w * (act @ Wd[e]); split-K x2
// Same 2-tiles-per-phase schedule; glls first, vmcnt(4).
// ---------------------------------------------------------------------------
__global__ __launch_bounds__(512, 4) void k_gemm2(
    const short* __restrict__ act, const float* __restrict__ wd,
    const int* __restrict__ meta, const int* __restrict__ slot_tok,
    const float* __restrict__ slot_w, float* __restrict__ out) {
  int nch = meta[9];
  if (blockIdx.y >= nch) return;
  int ck = meta[16 + blockIdx.y];
  int e = ck & 255;
  int row0 = ck >> 8;
  int rows = min(BM, meta[1 + e] - row0);
  int h0 = blockIdx.x * BN2;
  int kbase = blockIdx.z * (I_ / SPLITK2);

  __shared__ short sA[4][BM * BK];   // 32KB ring-4, linear [row][k]
  __shared__ short sB[4][BN2 * BK];  // 16KB ring-4, swizzled [n][k]

  int tid = threadIdx.x;
  int lane = tid & 63;
  int w = tid >> 6;
  int wm = w >> 1, wn = w & 1;
  int lr = lane & 15;
  int lk = (lane >> 4) * 8;

  const float* wdE = wd + (size_t)e * I_ * H_;

  int ra = min(16 * w + (lane >> 2), rows - 1);
  const short* srcA = act + (size_t)(row0 + ra) * I_ + kbase + (lane & 3) * 8;
  int up = tid >> 5;
  int n2 = (tid & 31) * 2;
  const float* srcB = wdE + (size_t)(kbase + 2 * up) * H_ + h0 + n2;

  f32x4 acc[2][2];
#pragma unroll
  for (int mr = 0; mr < 2; ++mr)
#pragma unroll
    for (int nr = 0; nr < 2; ++nr)
      acc[mr][nr] = (f32x4){0.f, 0.f, 0.f, 0.f};

  float2 yA0[2], yA1[2], yB0[2], yB1[2];

  const int NT = (I_ / SPLITK2) / BK;   // 32

#define G2_GLL(T) gll16(srcA + (size_t)(T) * BK, &sA[(T) & 3][w * 512])
#define G2_LOADB(C, T) do {                                                    \
    C[0] = *(const float2*)(srcB + (size_t)((T) * BK) * H_);                   \
    C[1] = *(const float2*)(srcB + (size_t)((T) * BK + 1) * H_);               \
  } while (0)
#define G2_CONV(T, C) do {                                                     \
    char* dst_ = (char*)&sB[(T) & 3][0];                                       \
    *(unsigned*)(dst_ + bswz(n2, 4 * up))     = cvtpk(C[0].x, C[1].x);         \
    *(unsigned*)(dst_ + bswz(n2 + 1, 4 * up)) = cvtpk(C[0].y, C[1].y);         \
  } while (0)
#define G2_COMPUTE(T) do {                                                     \
    bf16x8 a0 = *(const bf16x8*)&sA[(T) & 3][(wm * 32 + lr) * BK + lk];        \
    bf16x8 a1 = *(const bf16x8*)&sA[(T) & 3][(wm * 32 + 16 + lr) * BK + lk];   \
    bf16x8 b0 = *(const bf16x8*)((const char*)&sB[(T) & 3][0]                  \
                                 + bswz(wn * 32 + lr, lk * 2));                \
    bf16x8 b1 = *(const bf16x8*)((const char*)&sB[(T) & 3][0]                  \
                                 + bswz(wn * 32 + 16 + lr, lk * 2));           \
    acc[0][0] = MFMA_BF16(a0, b0, acc[0][0], 0, 0, 0);                         \
    acc[0][1] = MFMA_BF16(a0, b1, acc[0][1], 0, 0, 0);                         \
    acc[1][0] = MFMA_BF16(a1, b0, acc[1][0], 0, 0, 0);                         \
    acc[1][1] = MFMA_BF16(a1, b1, acc[1][1], 0, 0, 0);                         \
  } while (0)
#define G2_PHASE(T0, LA, LB, CA, CB, BAR) do {                                 \
    if ((T0) + 2 < NT) { G2_GLL((T0) + 2); G2_GLL((T0) + 3); }                 \
    __builtin_amdgcn_sched_barrier(0);                                         \
    if ((T0) + 4 < NT) { G2_LOADB(LA, (T0) + 4); G2_LOADB(LB, (T0) + 5); }     \
    G2_COMPUTE(T0);                                                            \
    G2_COMPUTE((T0) + 1);                                                      \
    if ((T0) + 2 < NT) { G2_CONV((T0) + 2, CA); G2_CONV((T0) + 3, CB); }       \
    BAR();                                                                     \
  } while (0)

  // prologue
  G2_GLL(0); G2_GLL(1); G2_GLL(2); G2_GLL(3);
  G2_LOADB(yB0, 0); G2_LOADB(yB1, 1);
  G2_CONV(0, yB0); G2_CONV(1, yB1);
  G2_LOADB(yA0, 2); G2_LOADB(yA1, 3);
  drain_barrier();

  for (int T0 = 0; T0 < 28; T0 += 4) {
    G2_PHASE(T0,     yB0, yB1, yA0, yA1, pipe_barrier4);
    G2_PHASE(T0 + 2, yA0, yA1, yB0, yB1, pipe_barrier4);
  }
  G2_PHASE(28, yB0, yB1, yA0, yA1, drain_barrier);
  G2_PHASE(30, yA0, yA1, yB0, yB1, no_barrier);

#undef G2_PHASE
#undef G2_COMPUTE
#undef G2_CONV
#undef G2_LOADB
#undef G2_GLL

  // epilogue: scale by combine weight, scatter-add
#pragma unroll
  for (int mr = 0; mr < 2; ++mr) {
#pragma unroll
    for (int r = 0; r < 4; ++r) {
      int m = wm * 32 + mr * 16 + (lane >> 4) * 4 + r;
      if (m < rows) {
        int gs = row0 + m;
        float wc = slot_w[gs];
        int tok = slot_tok[gs];
#pragma unroll
        for (int nr = 0; nr < 2; ++nr)
          atomicAdd(&out[(size_t)tok * H_ + h0 + wn * 32 + nr * 16 + lr],
                    acc[mr][nr][r] * wc);
      }
    }
  }
}

// ---------------------------------------------------------------------------
extern "C" void kernel_launch(void* const* d_in, const int* in_sizes, int n_in,
                              void* d_out, int out_size, void* d_ws, size_t ws_size,
                              hipStream_t stream) {
  const float* hs   = (const float*)d_in[0];
  const float* aff  = (const float*)d_in[1];
  const int*   eidx = (const int*)d_in[2];
  const float* wg   = (const float*)d_in[3];
  const float* wu   = (const float*)d_in[4];
  const float* wd   = (const float*)d_in[5];
  float* out = (float*)d_out;

  char* ws = (char*)d_ws;
  int*   meta     = (int*)ws;
  int*   slot_tok = (int*)(ws + 256);
  float* slot_w   = (float*)(ws + 256 + NSLOT * 4);
  short* hs_bf    = (short*)(ws + 256 + NSLOT * 8);
  short* act      = (short*)(ws + 256 + NSLOT * 8 + (size_t)T_ * H_ * 2);

  hipMemsetAsync(d_out, 0, (size_t)out_size * sizeof(float), stream);
  k_prep_build<<<(T_ * H_) / (256 * 8), 256, 0, stream>>>(
      hs, hs_bf, aff, eidx, meta, slot_tok, slot_w);
  k_gemm1<<<dim3(I_ / BN1, NCHUNK_CAP), 256, 0, stream>>>(
      hs_bf, wg, wu, meta, slot_tok, act);
  k_gemm2<<<dim3(H_ / BN2, NCHUNK_CAP, SPLITK2), 512, 0, stream>>>(
      act, wd, meta, slot_tok, slot_w, out);
}